// Round 6
// baseline (385.207 us; speedup 1.0000x reference)
//
#include <hip/hip_runtime.h>
#include <hip/hip_bf16.h>
#include <math.h>

typedef __attribute__((ext_vector_type(16))) float f32x16;
typedef __attribute__((ext_vector_type(8))) int i32x8;
typedef __attribute__((ext_vector_type(4))) int i32x4;

#define BM 128
#define BN 128
#define BK 64
#define TEMP_INV 14.2857142857142857f   // 1/0.07
#define UNIT_SCALE 0x7f7f7f7f           // E8M0 127 -> x1.0 exact

// ---- async global->LDS, 16B per lane
static __device__ inline void async16(const void* g, void* l) {
  __builtin_amdgcn_global_load_lds(
      (const __attribute__((address_space(1))) unsigned int*)g,
      (__attribute__((address_space(3))) unsigned int*)l,
      16, 0, 0);
}

// ============================================================
// Kernel 1: L2-normalize rows of A and B (D=1024), emit fp8 e4m3
// (canonical row-major). Also zeroes pos/neg accumulators.
// ============================================================
__global__ __launch_bounds__(256) void normalize_rows(
    const float* __restrict__ a, const float* __restrict__ b,
    unsigned char* __restrict__ oa, unsigned char* __restrict__ ob,
    float* __restrict__ pos_acc, float* __restrict__ neg_acc,
    int N, int D) {
  const int blk = blockIdx.x;
  const float* in;
  unsigned char* out;
  if (blk < N) {
    in = a + (size_t)blk * D;
    out = oa + (size_t)blk * D;
    if (threadIdx.x == 0) { pos_acc[blk] = 0.f; neg_acc[blk] = 0.f; }
  } else {
    in = b + (size_t)(blk - N) * D;
    out = ob + (size_t)(blk - N) * D;
  }
  const int t = threadIdx.x;
  const float4 v = ((const float4*)in)[t];
  float ss = v.x * v.x + v.y * v.y + v.z * v.z + v.w * v.w;
#pragma unroll
  for (int m = 32; m >= 1; m >>= 1) ss += __shfl_xor(ss, m, 64);
  __shared__ float wsum[4];
  const int wave = t >> 6, lane = t & 63;
  if (lane == 0) wsum[wave] = ss;
  __syncthreads();
  const float tot = wsum[0] + wsum[1] + wsum[2] + wsum[3];
  const float inv = 1.0f / fmaxf(sqrtf(tot), 1e-12f);
  // pack 4 x fp8 e4m3 (OCP) into one dword
  int r = __builtin_amdgcn_cvt_pk_fp8_f32(v.x * inv, v.y * inv, 0, false);
  r = __builtin_amdgcn_cvt_pk_fp8_f32(v.z * inv, v.w * inv, r, true);
  ((int*)out)[t] = r;
}

// ============================================================
// Kernel 2: fused MX-fp8 MFMA GEMM (A[N,D] x B[M,D]^T) + exp epilogue.
// 128x128 tile, BK=64, double-buffered LDS, one barrier per K-iter.
// mfma_scale_f32_32x32x64_f8f6f4 with unity scales (exact x1.0):
//   wave computes 64x64 as 2x2 of 32x32 tiles; per phase per wave:
//   8 ds_read_b128 + 4 MFMA (vs 32 MFMA before -> far fewer issue slots).
// Fragment: lane l holds row (l&31), K-bytes [kh*32, kh*32+32), kh=l>>5
//   = two 16B LDS slots (XOR-swizzled: slot s of row r at s^(r&3);
//   bank math: 8 dwords/bank/instr = wave64-b128 structural min).
// C/D layout (32x32, shape-determined): col=lane&31,
//   row=(reg&3)+8*(reg>>2)+4*(lane>>5).
// ============================================================
__global__ __launch_bounds__(256, 4) void infonce_gemm(
    const unsigned char* __restrict__ A, const unsigned char* __restrict__ B,
    const int* __restrict__ la, const int* __restrict__ lb,
    float* __restrict__ pos_acc, float* __restrict__ neg_acc, int D) {
  __shared__ __align__(16) unsigned char sA[2][BM * BK];  // 2 x 8 KB
  __shared__ __align__(16) unsigned char sB[2][BN * BK];  // 2 x 8 KB

  const int tid = threadIdx.x;
  const int lane = tid & 63;
  const int wave = tid >> 6;
  const int wm = wave >> 1;  // 0..1
  const int wn = wave & 1;   // 0..1
  const int row0 = blockIdx.y * BM;
  const int col0 = blockIdx.x * BN;

  // staging: LDS slot s = tid (+256): row r = s>>2, phys pos p = s&3
  // holds global 16B slot h = p ^ (r&3) of the row's current K-64 group
  const int sr = tid >> 2;
  const int sh = (tid & 3) ^ (sr & 3);
  const unsigned char* gA0 = A + (size_t)(row0 + sr) * D + sh * 16;
  const unsigned char* gA1 = gA0 + (size_t)64 * D;
  const unsigned char* gB0 = B + (size_t)(col0 + sr) * D + sh * 16;
  const unsigned char* gB1 = gB0 + (size_t)64 * D;

  f32x16 acc[2][2] = {};

  const int l31 = lane & 31;
  const int kh2 = (lane >> 5) * 2;                 // first logical 16B slot
  const int off0 = ((kh2 ^ (l31 & 3)) * 16);       // physical (swizzled), loop-invariant

#define STAGE(bufi, kk)                             \
  do {                                              \
    async16(gA0 + (kk), &sA[bufi][tid * 16]);       \
    async16(gA1 + (kk), &sA[bufi][4096 + tid * 16]);\
    async16(gB0 + (kk), &sB[bufi][tid * 16]);       \
    async16(gB1 + (kk), &sB[bufi][4096 + tid * 16]);\
  } while (0)

  // load a lane's 32B fragment (row rr) from swizzled LDS: two b128
#define LOAD32(dst, bufp, rr)                                   \
  do {                                                          \
    const unsigned char* _p = &(bufp)[(rr) * BK];               \
    i32x4 _lo = *(const i32x4*)(_p + off0);                     \
    i32x4 _hi = *(const i32x4*)(_p + (off0 ^ 16));              \
    dst = (i32x8){_lo.x, _lo.y, _lo.z, _lo.w,                   \
                  _hi.x, _hi.y, _hi.z, _hi.w};                  \
  } while (0)

#define COMPUTE(bufi)                                                        \
  do {                                                                       \
    i32x8 b0, b1, a0, a1;                                                    \
    LOAD32(b0, sB[bufi], wn * 64 + 0 + l31);                                 \
    LOAD32(b1, sB[bufi], wn * 64 + 32 + l31);                                \
    LOAD32(a0, sA[bufi], wm * 64 + 0 + l31);                                 \
    LOAD32(a1, sA[bufi], wm * 64 + 32 + l31);                                \
    acc[0][0] = __builtin_amdgcn_mfma_scale_f32_32x32x64_f8f6f4(             \
        a0, b0, acc[0][0], 0, 0, 0, UNIT_SCALE, 0, UNIT_SCALE);              \
    acc[0][1] = __builtin_amdgcn_mfma_scale_f32_32x32x64_f8f6f4(             \
        a0, b1, acc[0][1], 0, 0, 0, UNIT_SCALE, 0, UNIT_SCALE);              \
    acc[1][0] = __builtin_amdgcn_mfma_scale_f32_32x32x64_f8f6f4(             \
        a1, b0, acc[1][0], 0, 0, 0, UNIT_SCALE, 0, UNIT_SCALE);              \
    acc[1][1] = __builtin_amdgcn_mfma_scale_f32_32x32x64_f8f6f4(             \
        a1, b1, acc[1][1], 0, 0, 0, UNIT_SCALE, 0, UNIT_SCALE);              \
  } while (0)

  STAGE(0, 0);
#pragma unroll 1
  for (int k0 = 0; k0 < D; k0 += 2 * BK) {
    __syncthreads();  // drains vmcnt: tile(k0) in buf 0; buf 1 free
    if (k0 + BK < D) STAGE(1, k0 + BK);
    COMPUTE(0);
    __syncthreads();  // drains vmcnt: tile(k0+BK) in buf 1; buf 0 free
    if (k0 + 2 * BK < D) STAGE(0, k0 + 2 * BK);
    COMPUTE(1);
  }

  // ---- epilogue: 32x32 C/D layout: col=lane&31, row=(reg&3)+8*(reg>>2)+4*h
  const int h = lane >> 5;
  const int lbj0 = lb[col0 + wn * 64 + l31];
  const int lbj1 = lb[col0 + wn * 64 + 32 + l31];

#pragma unroll
  for (int i = 0; i < 2; i++) {
#pragma unroll
    for (int reg = 0; reg < 16; reg++) {
      const int row = row0 + wm * 64 + i * 32 + (reg & 3) + 8 * (reg >> 2) + 4 * h;
      const int lav = la[row];
      float s0 = acc[i][0][reg] * TEMP_INV;
      float s1 = acc[i][1][reg] * TEMP_INV;
      s0 = fminf(fmaxf(s0, -50.f), 50.f);
      s1 = fminf(fmaxf(s1, -50.f), 50.f);
      const float e0 = __expf(s0);
      const float e1 = __expf(s1);
      float sneg = e0 + e1;
      float spos = (lav == lbj0 ? e0 : 0.f) + (lav == lbj1 ? e1 : 0.f);
      // reduce over 32 cols (lanes of this half-wave)
#pragma unroll
      for (int m = 16; m >= 1; m >>= 1) {
        sneg += __shfl_xor(sneg, m, 32);
        spos += __shfl_xor(spos, m, 32);
      }
      if (l31 == 0) {
        atomicAdd(&neg_acc[row], sneg);
        atomicAdd(&pos_acc[row], spos);
      }
    }
  }
}

// ============================================================
// Kernel 3: loss = mean( log(neg) - log(max(pos,1e-8)) )
// ============================================================
__global__ __launch_bounds__(1024) void final_reduce(
    const float* __restrict__ pos, const float* __restrict__ neg,
    float* __restrict__ out, int N) {
  double local = 0.0;
  const int t = threadIdx.x;
  for (int i = t; i < N / 4; i += 1024) {
    const float4 p4 = ((const float4*)pos)[i];
    const float4 n4 = ((const float4*)neg)[i];
    local += (double)(logf(n4.x) - logf(fmaxf(p4.x, 1e-8f)));
    local += (double)(logf(n4.y) - logf(fmaxf(p4.y, 1e-8f)));
    local += (double)(logf(n4.z) - logf(fmaxf(p4.z, 1e-8f)));
    local += (double)(logf(n4.w) - logf(fmaxf(p4.w, 1e-8f)));
  }
#pragma unroll
  for (int m = 32; m >= 1; m >>= 1) local += __shfl_xor(local, m, 64);
  __shared__ double wsum[16];
  const int wave = t >> 6, lane = t & 63;
  if (lane == 0) wsum[wave] = local;
  __syncthreads();
  if (t == 0) {
    double tot = 0.0;
#pragma unroll
    for (int w = 0; w < 16; w++) tot += wsum[w];
    out[0] = (float)(tot / (double)N);
  }
}

extern "C" void kernel_launch(void* const* d_in, const int* in_sizes, int n_in,
                              void* d_out, int out_size, void* d_ws, size_t ws_size,
                              hipStream_t stream) {
  const float* fa = (const float*)d_in[0];
  const float* fb = (const float*)d_in[1];
  const int* la = (const int*)d_in[2];
  const int* lb = (const int*)d_in[3];

  const int D = 1024;
  const int N = in_sizes[0] / D;  // 8192
  const int M = in_sizes[1] / D;  // 8192

  unsigned char* nA = (unsigned char*)d_ws;
  unsigned char* nB = nA + (size_t)N * D;
  float* pos = (float*)(nB + (size_t)M * D);
  float* neg = pos + N;

  normalize_rows<<<N + M, 256, 0, stream>>>(fa, fb, nA, nB, pos, neg, N, D);

  dim3 grid(M / BN, N / BM);
  infonce_gemm<<<grid, 256, 0, stream>>>(nA, nB, la, lb, pos, neg, D);

  final_reduce<<<1, 1024, 0, stream>>>(pos, neg, (float*)d_out, N);
}

// Round 7
// 358.688 us; speedup vs baseline: 1.0739x; 1.0739x over previous
//
#include <hip/hip_runtime.h>
#include <hip/hip_bf16.h>
#include <math.h>

typedef __attribute__((ext_vector_type(16))) float f32x16;
typedef __attribute__((ext_vector_type(8))) int i32x8;
typedef __attribute__((ext_vector_type(4))) int i32x4;

#define BM 128
#define BN 128
#define BK 64
#define TEMP_INV 14.2857142857142857f   // 1/0.07
#define UNIT_SCALE 0x7f7f7f7f           // E8M0 127 -> x1.0 exact

union frag32 {
  i32x8 v8;
  struct { i32x4 lo; i32x4 hi; } s;
};

// ---- async global->LDS, 16B per lane
static __device__ inline void async16(const void* g, void* l) {
  __builtin_amdgcn_global_load_lds(
      (const __attribute__((address_space(1))) unsigned int*)g,
      (__attribute__((address_space(3))) unsigned int*)l,
      16, 0, 0);
}

// ============================================================
// Kernel 1: L2-normalize rows of A and B (D=1024), emit fp8 e4m3
// (canonical row-major). Also zeroes pos/neg accumulators.
// ============================================================
__global__ __launch_bounds__(256) void normalize_rows(
    const float* __restrict__ a, const float* __restrict__ b,
    unsigned char* __restrict__ oa, unsigned char* __restrict__ ob,
    float* __restrict__ pos_acc, float* __restrict__ neg_acc,
    int N, int D) {
  const int blk = blockIdx.x;
  const float* in;
  unsigned char* out;
  if (blk < N) {
    in = a + (size_t)blk * D;
    out = oa + (size_t)blk * D;
    if (threadIdx.x == 0) { pos_acc[blk] = 0.f; neg_acc[blk] = 0.f; }
  } else {
    in = b + (size_t)(blk - N) * D;
    out = ob + (size_t)(blk - N) * D;
  }
  const int t = threadIdx.x;
  const float4 v = ((const float4*)in)[t];
  float ss = v.x * v.x + v.y * v.y + v.z * v.z + v.w * v.w;
#pragma unroll
  for (int m = 32; m >= 1; m >>= 1) ss += __shfl_xor(ss, m, 64);
  __shared__ float wsum[4];
  const int wave = t >> 6, lane = t & 63;
  if (lane == 0) wsum[wave] = ss;
  __syncthreads();
  const float tot = wsum[0] + wsum[1] + wsum[2] + wsum[3];
  const float inv = 1.0f / fmaxf(sqrtf(tot), 1e-12f);
  // pack 4 x fp8 e4m3 (OCP) into one dword
  int r = __builtin_amdgcn_cvt_pk_fp8_f32(v.x * inv, v.y * inv, 0, false);
  r = __builtin_amdgcn_cvt_pk_fp8_f32(v.z * inv, v.w * inv, r, true);
  ((int*)out)[t] = r;
}

// ============================================================
// Kernel 2: fused MX-fp8 MFMA GEMM (A[N,D] x B[M,D]^T) + exp epilogue.
// 128x128 tile, BK=64, double-buffered LDS, one barrier per K-iter.
// mfma_scale_f32_32x32x64_f8f6f4, unity scales (exact x1.0).
//
// LDS swizzle v2 (fixes R6's 3x conflict regression): physical slot p
// of row r holds logical 16B slot  s = p ^ w(r),  w(r) = (r>>1)&3.
// Read pattern (row = l31, K-half = lane>>5): p_lo = kh2 ^ ((l31>>1)&3)
//  -> per (row-parity, slot-group): exactly 8 lanes = 8 dwords/bank
//  = wave64-b128 structural floor (R6's w(r)=r&3 put 8 lanes on HALF
//  the groups because kh2 only spans {0,2}).
// Per phase per wave: 8 ds_read_b128 + 4 MFMA.
// C/D layout (32x32): col=lane&31, row=(reg&3)+8*(reg>>2)+4*(lane>>5).
// ============================================================
__global__ __launch_bounds__(256, 4) void infonce_gemm(
    const unsigned char* __restrict__ A, const unsigned char* __restrict__ B,
    const int* __restrict__ la, const int* __restrict__ lb,
    float* __restrict__ pos_acc, float* __restrict__ neg_acc, int D) {
  __shared__ __align__(16) unsigned char sA[2][BM * BK];  // 2 x 8 KB
  __shared__ __align__(16) unsigned char sB[2][BN * BK];  // 2 x 8 KB

  const int tid = threadIdx.x;
  const int lane = tid & 63;
  const int wave = tid >> 6;
  const int wm = wave >> 1;  // 0..1
  const int wn = wave & 1;   // 0..1
  const int row0 = blockIdx.y * BM;
  const int col0 = blockIdx.x * BN;

  // staging: thread t writes phys 16B slot (row t>>2, p = t&3), which
  // holds global slot sh = p ^ w(row) = (t&3) ^ ((t>>3)&3).
  // (row+64 has the same w: 64>>1 = 32 == 0 mod 4.)
  const int sr = tid >> 2;
  const int sh = (tid & 3) ^ ((tid >> 3) & 3);
  const unsigned char* gA0 = A + (size_t)(row0 + sr) * D + sh * 16;
  const unsigned char* gA1 = gA0 + (size_t)64 * D;
  const unsigned char* gB0 = B + (size_t)(col0 + sr) * D + sh * 16;
  const unsigned char* gB1 = gB0 + (size_t)64 * D;

  f32x16 acc[2][2] = {};

  const int l31 = lane & 31;
  const int kh2 = (lane >> 5) * 2;              // logical first 16B slot
  const int wrow = (l31 >> 1) & 3;              // w(row): rows differ by mult of 32
  const int off_lo = ((kh2 ^ wrow) * 16);       // physical, loop-invariant

#define STAGE(bufi, kk)                             \
  do {                                              \
    async16(gA0 + (kk), &sA[bufi][tid * 16]);       \
    async16(gA1 + (kk), &sA[bufi][4096 + tid * 16]);\
    async16(gB0 + (kk), &sB[bufi][tid * 16]);       \
    async16(gB1 + (kk), &sB[bufi][4096 + tid * 16]);\
  } while (0)

  // lane's 32B fragment (row rr): logical slots kh2 -> phys off_lo,
  // kh2+1 -> phys off_lo^16
#define LOAD32(dst, bufp, rr)                                   \
  do {                                                          \
    const unsigned char* _p = &(bufp)[(rr) * BK];               \
    frag32 _f;                                                  \
    _f.s.lo = *(const i32x4*)(_p + off_lo);                     \
    _f.s.hi = *(const i32x4*)(_p + (off_lo ^ 16));              \
    dst = _f.v8;                                                \
  } while (0)

#define COMPUTE(bufi)                                                        \
  do {                                                                       \
    i32x8 b0, b1, a0, a1;                                                    \
    LOAD32(b0, sB[bufi], wn * 64 + 0 + l31);                                 \
    LOAD32(b1, sB[bufi], wn * 64 + 32 + l31);                                \
    LOAD32(a0, sA[bufi], wm * 64 + 0 + l31);                                 \
    LOAD32(a1, sA[bufi], wm * 64 + 32 + l31);                                \
    acc[0][0] = __builtin_amdgcn_mfma_scale_f32_32x32x64_f8f6f4(             \
        a0, b0, acc[0][0], 0, 0, 0, UNIT_SCALE, 0, UNIT_SCALE);              \
    acc[0][1] = __builtin_amdgcn_mfma_scale_f32_32x32x64_f8f6f4(             \
        a0, b1, acc[0][1], 0, 0, 0, UNIT_SCALE, 0, UNIT_SCALE);              \
    acc[1][0] = __builtin_amdgcn_mfma_scale_f32_32x32x64_f8f6f4(             \
        a1, b0, acc[1][0], 0, 0, 0, UNIT_SCALE, 0, UNIT_SCALE);              \
    acc[1][1] = __builtin_amdgcn_mfma_scale_f32_32x32x64_f8f6f4(             \
        a1, b1, acc[1][1], 0, 0, 0, UNIT_SCALE, 0, UNIT_SCALE);              \
  } while (0)

  STAGE(0, 0);
#pragma unroll 1
  for (int k0 = 0; k0 < D; k0 += 2 * BK) {
    __syncthreads();  // drains vmcnt: tile(k0) in buf 0; buf 1 free
    if (k0 + BK < D) STAGE(1, k0 + BK);
    COMPUTE(0);
    __syncthreads();  // drains vmcnt: tile(k0+BK) in buf 1; buf 0 free
    if (k0 + 2 * BK < D) STAGE(0, k0 + 2 * BK);
    COMPUTE(1);
  }

  // ---- epilogue: 32x32 C/D layout: col=lane&31, row=(reg&3)+8*(reg>>2)+4*h
  const int h = lane >> 5;
  const int lbj0 = lb[col0 + wn * 64 + l31];
  const int lbj1 = lb[col0 + wn * 64 + 32 + l31];

#pragma unroll
  for (int i = 0; i < 2; i++) {
#pragma unroll
    for (int reg = 0; reg < 16; reg++) {
      const int row = row0 + wm * 64 + i * 32 + (reg & 3) + 8 * (reg >> 2) + 4 * h;
      const int lav = la[row];
      float s0 = acc[i][0][reg] * TEMP_INV;
      float s1 = acc[i][1][reg] * TEMP_INV;
      s0 = fminf(fmaxf(s0, -50.f), 50.f);
      s1 = fminf(fmaxf(s1, -50.f), 50.f);
      const float e0 = __expf(s0);
      const float e1 = __expf(s1);
      float sneg = e0 + e1;
      float spos = (lav == lbj0 ? e0 : 0.f) + (lav == lbj1 ? e1 : 0.f);
      // reduce over 32 cols (lanes of this half-wave)
#pragma unroll
      for (int m = 16; m >= 1; m >>= 1) {
        sneg += __shfl_xor(sneg, m, 32);
        spos += __shfl_xor(spos, m, 32);
      }
      if (l31 == 0) {
        atomicAdd(&neg_acc[row], sneg);
        atomicAdd(&pos_acc[row], spos);
      }
    }
  }
}

// ============================================================
// Kernel 3: loss = mean( log(neg) - log(max(pos,1e-8)) )
// ============================================================
__global__ __launch_bounds__(1024) void final_reduce(
    const float* __restrict__ pos, const float* __restrict__ neg,
    float* __restrict__ out, int N) {
  double local = 0.0;
  const int t = threadIdx.x;
  for (int i = t; i < N / 4; i += 1024) {
    const float4 p4 = ((const float4*)pos)[i];
    const float4 n4 = ((const float4*)neg)[i];
    local += (double)(logf(n4.x) - logf(fmaxf(p4.x, 1e-8f)));
    local += (double)(logf(n4.y) - logf(fmaxf(p4.y, 1e-8f)));
    local += (double)(logf(n4.z) - logf(fmaxf(p4.z, 1e-8f)));
    local += (double)(logf(n4.w) - logf(fmaxf(p4.w, 1e-8f)));
  }
#pragma unroll
  for (int m = 32; m >= 1; m >>= 1) local += __shfl_xor(local, m, 64);
  __shared__ double wsum[16];
  const int wave = t >> 6, lane = t & 63;
  if (lane == 0) wsum[wave] = local;
  __syncthreads();
  if (t == 0) {
    double tot = 0.0;
#pragma unroll
    for (int w = 0; w < 16; w++) tot += wsum[w];
    out[0] = (float)(tot / (double)N);
  }
}

extern "C" void kernel_launch(void* const* d_in, const int* in_sizes, int n_in,
                              void* d_out, int out_size, void* d_ws, size_t ws_size,
                              hipStream_t stream) {
  const float* fa = (const float*)d_in[0];
  const float* fb = (const float*)d_in[1];
  const int* la = (const int*)d_in[2];
  const int* lb = (const int*)d_in[3];

  const int D = 1024;
  const int N = in_sizes[0] / D;  // 8192
  const int M = in_sizes[1] / D;  // 8192

  unsigned char* nA = (unsigned char*)d_ws;
  unsigned char* nB = nA + (size_t)N * D;
  float* pos = (float*)(nB + (size_t)M * D);
  float* neg = pos + N;

  normalize_rows<<<N + M, 256, 0, stream>>>(fa, fb, nA, nB, pos, neg, N, D);

  dim3 grid(M / BN, N / BM);
  infonce_gemm<<<grid, 256, 0, stream>>>(nA, nB, la, lb, pos, neg, D);

  final_reduce<<<1, 1024, 0, stream>>>(pos, neg, (float*)d_out, N);
}

// Round 8
// 343.130 us; speedup vs baseline: 1.1226x; 1.0453x over previous
//
#include <hip/hip_runtime.h>
#include <hip/hip_bf16.h>
#include <math.h>

typedef __attribute__((ext_vector_type(4))) float f32x4;
typedef __attribute__((ext_vector_type(2))) long lx2;

#define TEMP_INV 14.2857142857142857f   // 1/0.07

// ============================================================
// Tiled fragment layout (both nA and nB, 8 MB each):
//   tile (rt, kg) = rows [rt*16, rt*16+16) x K-bytes [kg*64, kg*64+64)
//   stored as 1 KB at byte ((rt*16 + kg)*1024); slot s (=lane) holds 16 B:
//   row rt*16+(s&15), K-halves q=(s>>4): bytes [kg*64+q*8,+8) ++ [kg*64+32+q*8,+8)
// => one global_load_dwordx4 per wave per MFMA-tile = 1 KB fully coalesced,
//    and the 16 B is exactly the lane's A/B fragment for a K-64 step
//    (lo 8 B -> 16x16x32 k-half 0, hi 8 B -> k-half 1).
// ============================================================

// ============================================================
// Kernel 1: L2-normalize rows of A and B (D=1024), emit fp8 e4m3
// in the tiled fragment layout. Also zeroes pos/neg accumulators.
// ============================================================
__global__ __launch_bounds__(256) void normalize_rows(
    const float* __restrict__ a, const float* __restrict__ b,
    unsigned char* __restrict__ oa, unsigned char* __restrict__ ob,
    float* __restrict__ pos_acc, float* __restrict__ neg_acc,
    int N, int D) {
  const int blk = blockIdx.x;
  const float* in;
  unsigned char* out;
  int row;
  if (blk < N) {
    row = blk;
    in = a + (size_t)row * D;
    out = oa;
    if (threadIdx.x == 0) { pos_acc[row] = 0.f; neg_acc[row] = 0.f; }
  } else {
    row = blk - N;
    in = b + (size_t)row * D;
    out = ob;
  }
  const int t = threadIdx.x;
  const float4 v = ((const float4*)in)[t];
  float ss = v.x * v.x + v.y * v.y + v.z * v.z + v.w * v.w;
#pragma unroll
  for (int m = 32; m >= 1; m >>= 1) ss += __shfl_xor(ss, m, 64);
  __shared__ float wsum[4];
  const int wave = t >> 6, lane = t & 63;
  if (lane == 0) wsum[wave] = ss;
  __syncthreads();
  const float tot = wsum[0] + wsum[1] + wsum[2] + wsum[3];
  const float inv = 1.0f / fmaxf(sqrtf(tot), 1e-12f);
  // pack 4 x fp8 e4m3 (OCP) into one dword (K bytes 4t..4t+3 of this row)
  int r = __builtin_amdgcn_cvt_pk_fp8_f32(v.x * inv, v.y * inv, 0, false);
  r = __builtin_amdgcn_cvt_pk_fp8_f32(v.z * inv, v.w * inv, r, true);
  // tiled-layout dword index:
  //   rt = row>>4, r15 = row&15, kg = t>>4, b = (t&15)*4,
  //   h = (t>>3)&1, q = (t&7)>>1, o = t&1, slot = q*16 + r15
  const int rt = row >> 4, r15 = row & 15;
  const int kg = t >> 4;
  const int h = (t >> 3) & 1, q = (t & 7) >> 1, o = t & 1;
  const int slot = q * 16 + r15;
  const size_t outIdx = (size_t)(rt * 16 + kg) * 256 + slot * 4 + h * 2 + o;
  ((int*)out)[outIdx] = r;
}

// ============================================================
// Kernel 2: fused fp8 MFMA GEMM (A[N,D] x B[M,D]^T) + exp epilogue.
// BARRIER-FREE: no LDS, fragments loaded global->VGPR directly from
// the tiled layout (one dwordx4 per MFMA-tile per wave, 1 KB coalesced).
// 128x128 block tile, 4 waves 2x2 (64x64/wave = 4x4 MFMA tiles),
// K-loop fully unrolled, distance-1 register prefetch: the compiler
// inserts fine-grained vmcnt(N) per fragment use (no vmcnt(0) drain,
// no s_barrier -- the stall structure of R1-R7 is gone).
// Cost: A/B panels each read by 2 waves -> 2x L2 traffic (~2.1 GB,
// ~58 us of L2 BW, overlapped with ~67 us MFMA-pipe floor).
// C/D layout (16x16): col=lane&15, row=(lane>>4)*4+reg.
// ============================================================
__global__ __launch_bounds__(256, 3) void infonce_gemm(
    const unsigned char* __restrict__ A, const unsigned char* __restrict__ B,
    const int* __restrict__ la, const int* __restrict__ lb,
    float* __restrict__ pos_acc, float* __restrict__ neg_acc) {
  const int tid = threadIdx.x;
  const int lane = tid & 63;
  const int wave = tid >> 6;
  const int wm = wave >> 1;  // 0..1
  const int wn = wave & 1;   // 0..1
  const int row0 = blockIdx.y * 128;
  const int col0 = blockIdx.x * 128;

  // fragment base pointers: tile row-index rt, tile (rt,kg) at (rt*16+kg)*1024
  const unsigned char* pa[4];
  const unsigned char* pb[4];
#pragma unroll
  for (int i = 0; i < 4; i++) {
    pa[i] = A + ((size_t)(blockIdx.y * 8 + wm * 4 + i) * 16384) + lane * 16;
    pb[i] = B + ((size_t)(blockIdx.x * 8 + wn * 4 + i) * 16384) + lane * 16;
  }

  f32x4 acc[4][4] = {};

  lx2 af[4], bf[4], an[4], bn[4];
#pragma unroll
  for (int i = 0; i < 4; i++) {
    af[i] = *(const lx2*)(pa[i]);
    bf[i] = *(const lx2*)(pb[i]);
  }

#pragma unroll
  for (int kg = 0; kg < 16; kg++) {
    if (kg < 15) {
#pragma unroll
      for (int i = 0; i < 4; i++) {
        an[i] = *(const lx2*)(pa[i] + (kg + 1) * 1024);
        bn[i] = *(const lx2*)(pb[i] + (kg + 1) * 1024);
      }
    }
#pragma unroll
    for (int i = 0; i < 4; i++)
#pragma unroll
      for (int j = 0; j < 4; j++) {
        acc[i][j] = __builtin_amdgcn_mfma_f32_16x16x32_fp8_fp8(
            af[i].x, bf[j].x, acc[i][j], 0, 0, 0);
        acc[i][j] = __builtin_amdgcn_mfma_f32_16x16x32_fp8_fp8(
            af[i].y, bf[j].y, acc[i][j], 0, 0, 0);
      }
#pragma unroll
    for (int i = 0; i < 4; i++) { af[i] = an[i]; bf[i] = bn[i]; }
  }

  // ---- epilogue: C/D layout col = lane&15, row = quad*4 + reg
  const int q = lane >> 4;
  const int l15 = lane & 15;
  int lbv[4];
#pragma unroll
  for (int j = 0; j < 4; j++) lbv[j] = lb[col0 + wn * 64 + j * 16 + l15];

#pragma unroll
  for (int i = 0; i < 4; i++) {
#pragma unroll
    for (int r = 0; r < 4; r++) {
      const int row = row0 + wm * 64 + i * 16 + q * 4 + r;
      const int lav = la[row];
      float sneg = 0.f, spos = 0.f;
#pragma unroll
      for (int j = 0; j < 4; j++) {
        float s = acc[i][j][r] * TEMP_INV;
        s = fminf(fmaxf(s, -50.f), 50.f);
        const float e = __expf(s);
        sneg += e;
        if (lav == lbv[j]) spos += e;
      }
      // reduce over the 16 lanes of this quad (cols 0..15 of the tiles)
#pragma unroll
      for (int m = 8; m >= 1; m >>= 1) {
        sneg += __shfl_xor(sneg, m, 16);
        spos += __shfl_xor(spos, m, 16);
      }
      if (l15 == 0) {
        atomicAdd(&neg_acc[row], sneg);
        atomicAdd(&pos_acc[row], spos);
      }
    }
  }
}

// ============================================================
// Kernel 3: loss = mean( log(neg) - log(max(pos,1e-8)) )
// ============================================================
__global__ __launch_bounds__(1024) void final_reduce(
    const float* __restrict__ pos, const float* __restrict__ neg,
    float* __restrict__ out, int N) {
  double local = 0.0;
  const int t = threadIdx.x;
  for (int i = t; i < N / 4; i += 1024) {
    const float4 p4 = ((const float4*)pos)[i];
    const float4 n4 = ((const float4*)neg)[i];
    local += (double)(logf(n4.x) - logf(fmaxf(p4.x, 1e-8f)));
    local += (double)(logf(n4.y) - logf(fmaxf(p4.y, 1e-8f)));
    local += (double)(logf(n4.z) - logf(fmaxf(p4.z, 1e-8f)));
    local += (double)(logf(n4.w) - logf(fmaxf(p4.w, 1e-8f)));
  }
#pragma unroll
  for (int m = 32; m >= 1; m >>= 1) local += __shfl_xor(local, m, 64);
  __shared__ double wsum[16];
  const int wave = t >> 6, lane = t & 63;
  if (lane == 0) wsum[wave] = local;
  __syncthreads();
  if (t == 0) {
    double tot = 0.0;
#pragma unroll
    for (int w = 0; w < 16; w++) tot += wsum[w];
    out[0] = (float)(tot / (double)N);
  }
}

extern "C" void kernel_launch(void* const* d_in, const int* in_sizes, int n_in,
                              void* d_out, int out_size, void* d_ws, size_t ws_size,
                              hipStream_t stream) {
  const float* fa = (const float*)d_in[0];
  const float* fb = (const float*)d_in[1];
  const int* la = (const int*)d_in[2];
  const int* lb = (const int*)d_in[3];

  const int D = 1024;
  const int N = in_sizes[0] / D;  // 8192
  const int M = in_sizes[1] / D;  // 8192

  unsigned char* nA = (unsigned char*)d_ws;
  unsigned char* nB = nA + (size_t)N * D;
  float* pos = (float*)(nB + (size_t)M * D);
  float* neg = pos + N;

  normalize_rows<<<N + M, 256, 0, stream>>>(fa, fb, nA, nB, pos, neg, N, D);

  dim3 grid(M / 128, N / 128);
  infonce_gemm<<<grid, 256, 0, stream>>>(nA, nB, la, lb, pos, neg);

  final_reduce<<<1, 1024, 0, stream>>>(pos, neg, (float*)d_out, N);
}

// Round 9
// 282.841 us; speedup vs baseline: 1.3619x; 1.2132x over previous
//
#include <hip/hip_runtime.h>
#include <hip/hip_bf16.h>
#include <math.h>

typedef __attribute__((ext_vector_type(4))) float f32x4;
typedef __attribute__((ext_vector_type(4))) int i32x4;
typedef __attribute__((ext_vector_type(2))) long lx2;

#define BM 128
#define BN 128
#define BK 64
#define TEMP_INV 14.2857142857142857f   // 1/0.07

// s_waitcnt imm (gfx9 encoding): lgkmcnt(0), vmcnt=max(63), expcnt=max(7)
#define WAIT_LGKM0 0xC07F

// ============================================================
// Kernel 1: L2-normalize rows of A and B (D=1024), emit fp8 e4m3
// in K-INTERLEAVED layout (R5): within each 64-byte K-group, the 8B
// chunks are stored [0,4,1,5,2,6,3,7], so one 16B slot p holds chunks
// (p, p+4) = a lane's K-data for BOTH K-32 halves of a K-64 step.
// Also zeroes pos/neg accumulators.
// ============================================================
__global__ __launch_bounds__(256) void normalize_rows(
    const float* __restrict__ a, const float* __restrict__ b,
    unsigned char* __restrict__ oa, unsigned char* __restrict__ ob,
    float* __restrict__ pos_acc, float* __restrict__ neg_acc,
    int N, int D) {
  const int blk = blockIdx.x;
  const float* in;
  unsigned char* out;
  if (blk < N) {
    in = a + (size_t)blk * D;
    out = oa + (size_t)blk * D;
    if (threadIdx.x == 0) { pos_acc[blk] = 0.f; neg_acc[blk] = 0.f; }
  } else {
    in = b + (size_t)(blk - N) * D;
    out = ob + (size_t)(blk - N) * D;
  }
  const int t = threadIdx.x;
  const float4 v = ((const float4*)in)[t];
  float ss = v.x * v.x + v.y * v.y + v.z * v.z + v.w * v.w;
#pragma unroll
  for (int m = 32; m >= 1; m >>= 1) ss += __shfl_xor(ss, m, 64);
  __shared__ float wsum[4];
  const int wave = t >> 6, lane = t & 63;
  if (lane == 0) wsum[wave] = ss;
  __syncthreads();
  const float tot = wsum[0] + wsum[1] + wsum[2] + wsum[3];
  const float inv = 1.0f / fmaxf(sqrtf(tot), 1e-12f);
  int r = __builtin_amdgcn_cvt_pk_fp8_f32(v.x * inv, v.y * inv, 0, false);
  r = __builtin_amdgcn_cvt_pk_fp8_f32(v.z * inv, v.w * inv, r, true);
  // interleave: group g=t>>4, 8B-chunk c=(t>>1)&7, half o=t&1
  const int g = t >> 4, c = (t >> 1) & 7, o = t & 1;
  const int outIdx = g * 16 + ((c & 3) * 2 + (c >> 2)) * 2 + o;
  ((int*)out)[outIdx] = r;
}

// ============================================================
// Kernel 2: fused fp8 MFMA GEMM (A[N,D] x B[M,D]^T) + exp epilogue.
// R5 structure (128x128 tile, BK=64, K-interleaved fp8, swizzled LDS,
// dbuf, 16x16x32_fp8 MFMA, 16 phases) with ONE transport change:
//   global_load -> VGPR (issued a full phase early)  -> ds_write -> LDS
//   and RAW s_barrier (no vmcnt drain!) instead of __syncthreads.
// Explicit s_waitcnt lgkmcnt(0) fences ds_write visibility; the only
// vmcnt wait is the compiler's, placed at the ds_write that consumes
// the staged regs -- one full compute phase after issue. Staging
// loads thus stay in flight across barriers (the hipBLASLt pattern
// that __syncthreads' vmcnt(0) drain forbids).
// ============================================================
__global__ __launch_bounds__(256, 4) void infonce_gemm(
    const unsigned char* __restrict__ A, const unsigned char* __restrict__ B,
    const int* __restrict__ la, const int* __restrict__ lb,
    float* __restrict__ pos_acc, float* __restrict__ neg_acc, int D) {
  __shared__ __align__(16) unsigned char sA[2][BM * BK];  // 2 x 8 KB
  __shared__ __align__(16) unsigned char sB[2][BN * BK];  // 2 x 8 KB

  const int tid = threadIdx.x;
  const int lane = tid & 63;
  const int wave = tid >> 6;
  const int wm = wave >> 1;  // 0..1
  const int wn = wave & 1;   // 0..1
  const int row0 = blockIdx.y * BM;
  const int col0 = blockIdx.x * BN;

  // staging: thread t owns phys 16B slot (row t>>2, p=t&3) holding global
  // slot sh = p ^ (row&3) of the row's current K-64 group (R5 swizzle)
  const int sr = tid >> 2;
  const int sh = (tid & 3) ^ (sr & 3);
  const unsigned char* gA0 = A + (size_t)(row0 + sr) * D + sh * 16;
  const unsigned char* gA1 = gA0 + (size_t)64 * D;
  const unsigned char* gB0 = B + (size_t)(col0 + sr) * D + sh * 16;
  const unsigned char* gB1 = gB0 + (size_t)64 * D;

  f32x4 acc[4][4] = {};

  const int q = lane >> 4;    // 0..3
  const int l15 = lane & 15;  // 0..15
  const int inn = ((q ^ (l15 & 3)) * 16);  // swizzled, loop-invariant

  i32x4 ra0, ra1, rb0, rb1;   // staging registers (in flight across barriers)

#define LOADG(kk)                             \
  do {                                        \
    ra0 = *(const i32x4*)(gA0 + (kk));        \
    ra1 = *(const i32x4*)(gA1 + (kk));        \
    rb0 = *(const i32x4*)(gB0 + (kk));        \
    rb1 = *(const i32x4*)(gB1 + (kk));        \
  } while (0)

#define WRITELDS(bufi)                                   \
  do {                                                   \
    *(i32x4*)&sA[bufi][tid * 16] = ra0;                  \
    *(i32x4*)&sA[bufi][4096 + tid * 16] = ra1;           \
    *(i32x4*)&sB[bufi][tid * 16] = rb0;                  \
    *(i32x4*)&sB[bufi][4096 + tid * 16] = rb1;           \
  } while (0)

#define COMPUTE(bufi)                                                         \
  do {                                                                        \
    lx2 bv0 = *(const lx2*)&sB[bufi][(wn * 64 + 0 + l15) * BK + inn];         \
    lx2 bv1 = *(const lx2*)&sB[bufi][(wn * 64 + 16 + l15) * BK + inn];        \
    lx2 bv2 = *(const lx2*)&sB[bufi][(wn * 64 + 32 + l15) * BK + inn];        \
    lx2 bv3 = *(const lx2*)&sB[bufi][(wn * 64 + 48 + l15) * BK + inn];        \
    _Pragma("unroll") for (int i = 0; i < 4; i++) {                           \
      lx2 av = *(const lx2*)&sA[bufi][(wm * 64 + i * 16 + l15) * BK + inn];   \
      acc[i][0] = __builtin_amdgcn_mfma_f32_16x16x32_fp8_fp8(av.x, bv0.x, acc[i][0], 0, 0, 0); \
      acc[i][1] = __builtin_amdgcn_mfma_f32_16x16x32_fp8_fp8(av.x, bv1.x, acc[i][1], 0, 0, 0); \
      acc[i][2] = __builtin_amdgcn_mfma_f32_16x16x32_fp8_fp8(av.x, bv2.x, acc[i][2], 0, 0, 0); \
      acc[i][3] = __builtin_amdgcn_mfma_f32_16x16x32_fp8_fp8(av.x, bv3.x, acc[i][3], 0, 0, 0); \
      acc[i][0] = __builtin_amdgcn_mfma_f32_16x16x32_fp8_fp8(av.y, bv0.y, acc[i][0], 0, 0, 0); \
      acc[i][1] = __builtin_amdgcn_mfma_f32_16x16x32_fp8_fp8(av.y, bv1.y, acc[i][1], 0, 0, 0); \
      acc[i][2] = __builtin_amdgcn_mfma_f32_16x16x32_fp8_fp8(av.y, bv2.y, acc[i][2], 0, 0, 0); \
      acc[i][3] = __builtin_amdgcn_mfma_f32_16x16x32_fp8_fp8(av.y, bv3.y, acc[i][3], 0, 0, 0); \
    }                                                                         \
  } while (0)

  LOADG(0);
#pragma unroll 1
  for (int k0 = 0; k0 < D; k0 += 2 * BK) {
    // phase A: tile k0 -> buf0
    WRITELDS(0);                             // compiler waits vmcnt for ra/rb
    __builtin_amdgcn_s_waitcnt(WAIT_LGKM0);  // ds_write visible
    __builtin_amdgcn_s_barrier();
    LOADG(k0 + BK);                          // in flight across next barrier
    COMPUTE(0);
    __builtin_amdgcn_s_barrier();            // end-of-read buf0 (no vmcnt drain)

    // phase B: tile k0+BK -> buf1
    WRITELDS(1);
    __builtin_amdgcn_s_waitcnt(WAIT_LGKM0);
    __builtin_amdgcn_s_barrier();
    if (k0 + 2 * BK < D) LOADG(k0 + 2 * BK);
    COMPUTE(1);
    __builtin_amdgcn_s_barrier();
  }

  // ---- epilogue: C/D layout col = lane&15, row = quad*4 + reg
  int lbv[4];
#pragma unroll
  for (int j = 0; j < 4; j++) lbv[j] = lb[col0 + wn * 64 + j * 16 + l15];

#pragma unroll
  for (int i = 0; i < 4; i++) {
#pragma unroll
    for (int r = 0; r < 4; r++) {
      const int row = row0 + wm * 64 + i * 16 + q * 4 + r;
      const int lav = la[row];
      float sneg = 0.f, spos = 0.f;
#pragma unroll
      for (int j = 0; j < 4; j++) {
        float s = acc[i][j][r] * TEMP_INV;
        s = fminf(fmaxf(s, -50.f), 50.f);
        const float e = __expf(s);
        sneg += e;
        if (lav == lbv[j]) spos += e;
      }
#pragma unroll
      for (int m = 8; m >= 1; m >>= 1) {
        sneg += __shfl_xor(sneg, m, 16);
        spos += __shfl_xor(spos, m, 16);
      }
      if (l15 == 0) {
        atomicAdd(&neg_acc[row], sneg);
        atomicAdd(&pos_acc[row], spos);
      }
    }
  }
}

// ============================================================
// Kernel 3: loss = mean( log(neg) - log(max(pos,1e-8)) )
// ============================================================
__global__ __launch_bounds__(1024) void final_reduce(
    const float* __restrict__ pos, const float* __restrict__ neg,
    float* __restrict__ out, int N) {
  double local = 0.0;
  const int t = threadIdx.x;
  for (int i = t; i < N / 4; i += 1024) {
    const float4 p4 = ((const float4*)pos)[i];
    const float4 n4 = ((const float4*)neg)[i];
    local += (double)(logf(n4.x) - logf(fmaxf(p4.x, 1e-8f)));
    local += (double)(logf(n4.y) - logf(fmaxf(p4.y, 1e-8f)));
    local += (double)(logf(n4.z) - logf(fmaxf(p4.z, 1e-8f)));
    local += (double)(logf(n4.w) - logf(fmaxf(p4.w, 1e-8f)));
  }
#pragma unroll
  for (int m = 32; m >= 1; m >>= 1) local += __shfl_xor(local, m, 64);
  __shared__ double wsum[16];
  const int wave = t >> 6, lane = t & 63;
  if (lane == 0) wsum[wave] = local;
  __syncthreads();
  if (t == 0) {
    double tot = 0.0;
#pragma unroll
    for (int w = 0; w < 16; w++) tot += wsum[w];
    out[0] = (float)(tot / (double)N);
  }
}

extern "C" void kernel_launch(void* const* d_in, const int* in_sizes, int n_in,
                              void* d_out, int out_size, void* d_ws, size_t ws_size,
                              hipStream_t stream) {
  const float* fa = (const float*)d_in[0];
  const float* fb = (const float*)d_in[1];
  const int* la = (const int*)d_in[2];
  const int* lb = (const int*)d_in[3];

  const int D = 1024;
  const int N = in_sizes[0] / D;  // 8192
  const int M = in_sizes[1] / D;  // 8192

  unsigned char* nA = (unsigned char*)d_ws;
  unsigned char* nB = nA + (size_t)N * D;
  float* pos = (float*)(nB + (size_t)M * D);
  float* neg = pos + N;

  normalize_rows<<<N + M, 256, 0, stream>>>(fa, fb, nA, nB, pos, neg, N, D);

  dim3 grid(M / BN, N / BM);
  infonce_gemm<<<grid, 256, 0, stream>>>(nA, nB, la, lb, pos, neg, D);

  final_reduce<<<1, 1024, 0, stream>>>(pos, neg, (float*)d_out, N);
}

// Round 10
// 259.784 us; speedup vs baseline: 1.4828x; 1.0888x over previous
//
#include <hip/hip_runtime.h>
#include <hip/hip_bf16.h>
#include <math.h>

typedef __attribute__((ext_vector_type(4))) float f32x4;
typedef __attribute__((ext_vector_type(8))) int i32x8;
typedef __attribute__((ext_vector_type(4))) int i32x4;

#define BM 128
#define BN 128
#define BK 128
#define TEMP_INV 14.2857142857142857f   // 1/0.07
#define UNIT_SCALE 0x7f7f7f7f           // E8M0 127 -> x1.0 exact (R6/R7-verified)

union frag32 {
  i32x8 v8;
  struct { i32x4 lo; i32x4 hi; } s;
};

// ---- async global->LDS, 16B per lane (LDS dst = uniform base + lane*16;
// passing a tid-linear pointer satisfies this -- m97 pattern)
static __device__ inline void async16(const void* g, void* l) {
  __builtin_amdgcn_global_load_lds(
      (const __attribute__((address_space(1))) unsigned int*)g,
      (__attribute__((address_space(3))) unsigned int*)l,
      16, 0, 0);
}

// ============================================================
// Kernel 1: L2-normalize rows of A and B (D=1024), emit fp8 e4m3
// (plain row-major -- K=128 fragments are contiguous 32B, no interleave
// needed). Also zeroes pos/neg accumulators.
// ============================================================
__global__ __launch_bounds__(256) void normalize_rows(
    const float* __restrict__ a, const float* __restrict__ b,
    unsigned char* __restrict__ oa, unsigned char* __restrict__ ob,
    float* __restrict__ pos_acc, float* __restrict__ neg_acc,
    int N, int D) {
  const int blk = blockIdx.x;
  const float* in;
  unsigned char* out;
  if (blk < N) {
    in = a + (size_t)blk * D;
    out = oa + (size_t)blk * D;
    if (threadIdx.x == 0) { pos_acc[blk] = 0.f; neg_acc[blk] = 0.f; }
  } else {
    in = b + (size_t)(blk - N) * D;
    out = ob + (size_t)(blk - N) * D;
  }
  const int t = threadIdx.x;
  const float4 v = ((const float4*)in)[t];
  float ss = v.x * v.x + v.y * v.y + v.z * v.z + v.w * v.w;
#pragma unroll
  for (int m = 32; m >= 1; m >>= 1) ss += __shfl_xor(ss, m, 64);
  __shared__ float wsum[4];
  const int wave = t >> 6, lane = t & 63;
  if (lane == 0) wsum[wave] = ss;
  __syncthreads();
  const float tot = wsum[0] + wsum[1] + wsum[2] + wsum[3];
  const float inv = 1.0f / fmaxf(sqrtf(tot), 1e-12f);
  int r = __builtin_amdgcn_cvt_pk_fp8_f32(v.x * inv, v.y * inv, 0, false);
  r = __builtin_amdgcn_cvt_pk_fp8_f32(v.z * inv, v.w * inv, r, true);
  ((int*)out)[t] = r;
}

// ============================================================
// Kernel 2: fused MX-fp8 MFMA GEMM (A[N,D] x B[M,D]^T) + exp epilogue.
// m148 replication: mfma_scale_f32_16x16x128_f8f6f4 (K=128, 2x pipe
// rate), BK=128, SINGLE-buffered 32 KB LDS, m97 2-barrier skeleton,
// global_load_lds width-16 staging. 8 phases (half the barriers of R9),
// 16 MFMA + 16 ds_read_b128 per wave per phase.
//
// LDS slot swizzle: row r (128 B = 8 x 16B slots), logical slot s
// stored at phys  s ^ (r&7).
//  - read: lane (q=lane>>4, l15=lane&15) tile-row r = base+l15 needs
//    slots s0=2q, s1=2q+1 -> phys0=(2q)^(l15&7), phys1=phys0^1.
//    Per b128 instruction: (2q)^(l15&7) spans all 8 slot-groups,
//    8 lanes each = 8 dwords/bank = structural floor.
//  - staging call c (0..3): slot-id S = c*256+tid -> row S>>3,
//    phys p = tid&7, fetches logical l = p ^ (row&7) = (tid&7)^((tid>>3)&7).
// A/B fragment (16x16x128): lane holds row l15, K-bytes [q*32,q*32+32)
//  = logical slots 2q,2q+1 (lo/hi). C/D layout: the verified 16x16 map.
// ============================================================
__global__ __launch_bounds__(256, 3) void infonce_gemm(
    const unsigned char* __restrict__ A, const unsigned char* __restrict__ B,
    const int* __restrict__ la, const int* __restrict__ lb,
    float* __restrict__ pos_acc, float* __restrict__ neg_acc, int D) {
  __shared__ __align__(16) unsigned char sA[BM * BK];  // 16 KB
  __shared__ __align__(16) unsigned char sB[BN * BK];  // 16 KB

  const int tid = threadIdx.x;
  const int lane = tid & 63;
  const int wave = tid >> 6;
  const int wm = wave >> 1;  // 0..1
  const int wn = wave & 1;   // 0..1
  const int row0 = blockIdx.y * BM;
  const int col0 = blockIdx.x * BN;

  // staging: call c covers rows c*32 + (tid>>3); within-row logical 16B
  // slot l = (tid&7) ^ ((tid>>3)&7)
  const int srow = tid >> 3;
  const int sl = ((tid & 7) ^ (srow & 7)) * 16;
  const unsigned char* gA = A + (size_t)(row0 + srow) * D + sl;
  const unsigned char* gB = B + (size_t)(col0 + srow) * D + sl;

  f32x4 acc[4][4] = {};

  const int q = lane >> 4;    // 0..3
  const int l15 = lane & 15;  // 0..15
  const int phys0 = ((2 * q) ^ (l15 & 7)) * 16;  // loop-invariant

#define STAGE(kk)                                                   \
  do {                                                              \
    _Pragma("unroll") for (int c = 0; c < 4; c++) {                 \
      async16(gA + (size_t)c * 32 * 1024 + (kk),                    \
              &sA[(c * 256 + tid) * 16]);                           \
      async16(gB + (size_t)c * 32 * 1024 + (kk),                    \
              &sB[(c * 256 + tid) * 16]);                           \
    }                                                               \
  } while (0)

  // lane's 32B fragment for tile-row rr: logical slots (2q, 2q+1)
#define LOAD32(dst, bufp, rr)                                   \
  do {                                                          \
    const unsigned char* _p = &(bufp)[(rr) * BK];               \
    frag32 _f;                                                  \
    _f.s.lo = *(const i32x4*)(_p + phys0);                      \
    _f.s.hi = *(const i32x4*)(_p + (phys0 ^ 16));               \
    dst = _f.v8;                                                \
  } while (0)

#pragma unroll 1
  for (int k0 = 0; k0 < D; k0 += BK) {
    STAGE(k0);
    __syncthreads();  // drain global_load_lds; tile visible
    i32x8 bf0, bf1, bf2, bf3;
    LOAD32(bf0, sB, wn * 64 + 0 + l15);
    LOAD32(bf1, sB, wn * 64 + 16 + l15);
    LOAD32(bf2, sB, wn * 64 + 32 + l15);
    LOAD32(bf3, sB, wn * 64 + 48 + l15);
#pragma unroll
    for (int i = 0; i < 4; i++) {
      i32x8 af;
      LOAD32(af, sA, wm * 64 + i * 16 + l15);
      acc[i][0] = __builtin_amdgcn_mfma_scale_f32_16x16x128_f8f6f4(
          af, bf0, acc[i][0], 0, 0, 0, UNIT_SCALE, 0, UNIT_SCALE);
      acc[i][1] = __builtin_amdgcn_mfma_scale_f32_16x16x128_f8f6f4(
          af, bf1, acc[i][1], 0, 0, 0, UNIT_SCALE, 0, UNIT_SCALE);
      acc[i][2] = __builtin_amdgcn_mfma_scale_f32_16x16x128_f8f6f4(
          af, bf2, acc[i][2], 0, 0, 0, UNIT_SCALE, 0, UNIT_SCALE);
      acc[i][3] = __builtin_amdgcn_mfma_scale_f32_16x16x128_f8f6f4(
          af, bf3, acc[i][3], 0, 0, 0, UNIT_SCALE, 0, UNIT_SCALE);
    }
    __syncthreads();  // all reads done before next STAGE overwrites
  }

  // ---- epilogue: C/D layout col = lane&15, row = quad*4 + reg (verified)
  int lbv[4];
#pragma unroll
  for (int j = 0; j < 4; j++) lbv[j] = lb[col0 + wn * 64 + j * 16 + l15];

#pragma unroll
  for (int i = 0; i < 4; i++) {
#pragma unroll
    for (int r = 0; r < 4; r++) {
      const int row = row0 + wm * 64 + i * 16 + q * 4 + r;
      const int lav = la[row];
      float sneg = 0.f, spos = 0.f;
#pragma unroll
      for (int j = 0; j < 4; j++) {
        float s = acc[i][j][r] * TEMP_INV;
        s = fminf(fmaxf(s, -50.f), 50.f);
        const float e = __expf(s);
        sneg += e;
        if (lav == lbv[j]) spos += e;
      }
#pragma unroll
      for (int m = 8; m >= 1; m >>= 1) {
        sneg += __shfl_xor(sneg, m, 16);
        spos += __shfl_xor(spos, m, 16);
      }
      if (l15 == 0) {
        atomicAdd(&neg_acc[row], sneg);
        atomicAdd(&pos_acc[row], spos);
      }
    }
  }
}

// ============================================================
// Kernel 3: loss = mean( log(neg) - log(max(pos,1e-8)) )
// ============================================================
__global__ __launch_bounds__(1024) void final_reduce(
    const float* __restrict__ pos, const float* __restrict__ neg,
    float* __restrict__ out, int N) {
  double local = 0.0;
  const int t = threadIdx.x;
  for (int i = t; i < N / 4; i += 1024) {
    const float4 p4 = ((const float4*)pos)[i];
    const float4 n4 = ((const float4*)neg)[i];
    local += (double)(logf(n4.x) - logf(fmaxf(p4.x, 1e-8f)));
    local += (double)(logf(n4.y) - logf(fmaxf(p4.y, 1e-8f)));
    local += (double)(logf(n4.z) - logf(fmaxf(p4.z, 1e-8f)));
    local += (double)(logf(n4.w) - logf(fmaxf(p4.w, 1e-8f)));
  }
#pragma unroll
  for (int m = 32; m >= 1; m >>= 1) local += __shfl_xor(local, m, 64);
  __shared__ double wsum[16];
  const int wave = t >> 6, lane = t & 63;
  if (lane == 0) wsum[wave] = local;
  __syncthreads();
  if (t == 0) {
    double tot = 0.0;
#pragma unroll
    for (int w = 0; w < 16; w++) tot += wsum[w];
    out[0] = (float)(tot / (double)N);
  }
}

extern "C" void kernel_launch(void* const* d_in, const int* in_sizes, int n_in,
                              void* d_out, int out_size, void* d_ws, size_t ws_size,
                              hipStream_t stream) {
  const float* fa = (const float*)d_in[0];
  const float* fb = (const float*)d_in[1];
  const int* la = (const int*)d_in[2];
  const int* lb = (const int*)d_in[3];

  const int D = 1024;
  const int N = in_sizes[0] / D;  // 8192
  const int M = in_sizes[1] / D;  // 8192

  unsigned char* nA = (unsigned char*)d_ws;
  unsigned char* nB = nA + (size_t)N * D;
  float* pos = (float*)(nB + (size_t)M * D);
  float* neg = pos + N;

  normalize_rows<<<N + M, 256, 0, stream>>>(fa, fb, nA, nB, pos, neg, N, D);

  dim3 grid(M / BN, N / BM);
  infonce_gemm<<<grid, 256, 0, stream>>>(nA, nB, la, lb, pos, neg, D);

  final_reduce<<<1, 1024, 0, stream>>>(pos, neg, (float*)d_out, N);
}